// Round 5
// baseline (9851.145 us; speedup 1.0000x reference)
//
#include <hip/hip_runtime.h>
#include <cstdint>
#include <cstddef>

// ---------------------------------------------------------------------------
// Problem constants (ARU recurrence): B=32, S=1024, H=1024, 3H=3072
// ---------------------------------------------------------------------------
#define HID   1024
#define BATCH 32
#define SEQ   1024
#define NROWS 32768   /* BATCH*SEQ */
#define G3    3072
#define NWORK 32      /* recurrence worker WGs; WG g owns h-cols [32g,32g+32) */
#define HSLOT 32768   /* elements per h ring slot = BATCH*HID */

typedef __attribute__((ext_vector_type(8))) short bf16x8_t;
typedef __attribute__((ext_vector_type(4))) float f32x4_t;

__device__ __forceinline__ unsigned short f2bf(float f) {
  unsigned u = __float_as_uint(f);
  u += 0x7FFFu + ((u >> 16) & 1u);       // round-to-nearest-even
  return (unsigned short)(u >> 16);
}
__device__ __forceinline__ float bf2f(unsigned short s) {
  return __uint_as_float(((unsigned)s) << 16);
}

// write-through device-coherent 16-bit store: visible at the device coherence
// point (IF$) — VERIFIED protocol from the round-0 passing kernel.
__device__ __forceinline__ void store_short_wt(unsigned short* p, unsigned short v) {
  asm volatile("global_store_short %0, %1, off sc0 sc1"
               :: "v"(p), "v"((unsigned)v) : "memory");
}

// ---------------------------------------------------------------------------
// K0: transpose + cast  W (1024 x N) fp32  ->  WT (N x 1024) bf16
// ---------------------------------------------------------------------------
__global__ __launch_bounds__(256) void transpose_cast(const float* __restrict__ in,
                                                      unsigned short* __restrict__ out,
                                                      int N) {
  __shared__ float tile[32][33];
  int k0 = blockIdx.x * 32, n0 = blockIdx.y * 32;
  int tx = threadIdx.x, ty = threadIdx.y;   // (32,8)
#pragma unroll
  for (int i = 0; i < 4; ++i)
    tile[ty + 8 * i][tx] = in[(size_t)(k0 + ty + 8 * i) * N + n0 + tx];
  __syncthreads();
#pragma unroll
  for (int i = 0; i < 4; ++i)
    out[(size_t)(n0 + ty + 8 * i) * HID + k0 + tx] = f2bf(tile[tx][ty + 8 * i]);
}

// ---------------------------------------------------------------------------
// K1: e = bf16(embed[x])   (32768 x 1024)
// ---------------------------------------------------------------------------
__global__ __launch_bounds__(256) void gather_cast(const int* __restrict__ x,
                                                   const float* __restrict__ embed,
                                                   unsigned short* __restrict__ e) {
  int r = blockIdx.x;
  int t = threadIdx.x;
  int tok = x[r];
  const float4* src = (const float4*)(embed + (size_t)tok * HID);
  float4 v = src[t];
  ushort4 o;
  o.x = f2bf(v.x); o.y = f2bf(v.y); o.z = f2bf(v.z); o.w = f2bf(v.w);
  ((ushort4*)(e + (size_t)r * HID))[t] = o;
}

// ---------------------------------------------------------------------------
// K2: fused GEMM  C = e(32768x1024) @ B'(1024x4096)   [B' stored as (4096x1024)]
//     cols [0,3072): gate_x = C + bgx   (bf16 out)
//     cols [3072,4096): cand = tanh(C + bc) (bf16 out)
// ---------------------------------------------------------------------------
__global__ __launch_bounds__(256) void gemm_fused(const unsigned short* __restrict__ A,
                                                  const unsigned short* __restrict__ B,
                                                  const float* __restrict__ bgx,
                                                  const float* __restrict__ bc,
                                                  unsigned short* __restrict__ gx,
                                                  unsigned short* __restrict__ cand) {
  __shared__ unsigned short As[128 * 32];
  __shared__ unsigned short Bs[128 * 32];
  const int bm = blockIdx.x * 128, bn = blockIdx.y * 128;
  const int t = threadIdx.x;
  const int wave = t >> 6, lane = t & 63;
  const int q = lane >> 4, nidx = lane & 15;
  const int wm = (wave & 1) * 64, wn = (wave >> 1) * 64;
  const int sr = t >> 2;
  const int kofs = (t & 3) * 8;

  f32x4_t acc[4][4];
#pragma unroll
  for (int i = 0; i < 4; ++i)
#pragma unroll
    for (int j = 0; j < 4; ++j) acc[i][j] = (f32x4_t){0.f, 0.f, 0.f, 0.f};

#pragma unroll 1
  for (int kt = 0; kt < HID; kt += 32) {
    __syncthreads();
#pragma unroll
    for (int c = 0; c < 2; ++c) {
      int row = c * 64 + sr;
      *(uint4*)(&As[row * 32 + kofs]) = *(const uint4*)(&A[(size_t)(bm + row) * HID + kt + kofs]);
      *(uint4*)(&Bs[row * 32 + kofs]) = *(const uint4*)(&B[(size_t)(bn + row) * HID + kt + kofs]);
    }
    __syncthreads();
    bf16x8_t af[4], bfr[4];
#pragma unroll
    for (int i = 0; i < 4; ++i)
      af[i] = *(const bf16x8_t*)(&As[(wm + i * 16 + nidx) * 32 + q * 8]);
#pragma unroll
    for (int j = 0; j < 4; ++j)
      bfr[j] = *(const bf16x8_t*)(&Bs[(wn + j * 16 + nidx) * 32 + q * 8]);
#pragma unroll
    for (int i = 0; i < 4; ++i)
#pragma unroll
      for (int j = 0; j < 4; ++j)
        acc[i][j] = __builtin_amdgcn_mfma_f32_16x16x32_bf16(af[i], bfr[j], acc[i][j], 0, 0, 0);
  }

#pragma unroll
  for (int i = 0; i < 4; ++i) {
#pragma unroll
    for (int j = 0; j < 4; ++j) {
#pragma unroll
      for (int reg = 0; reg < 4; ++reg) {
        int m = bm + wm + i * 16 + q * 4 + reg;
        int n = bn + wn + j * 16 + nidx;
        float v = acc[i][j][reg];
        if (n < G3) {
          gx[(size_t)m * G3 + n] = f2bf(v + bgx[n]);
        } else {
          int nc = n - G3;
          cand[(size_t)m * HID + nc] = f2bf(tanhf(v + bc[nc]));
        }
      }
    }
  }
}

// ---------------------------------------------------------------------------
// K3a: zero flags[32]  (ring slot 0 is never read: t=0 skips the matvec)
// ---------------------------------------------------------------------------
__global__ __launch_bounds__(64) void init_state(unsigned int* __restrict__ fx) {
  int t = threadIdx.x;
  if (t < 32) fx[t] = 0u;
}

// ---------------------------------------------------------------------------
// K3b: canary — diagnostic sentinel, overwritten by a successful recurrence.
// absmax ~1e6 next round  => recurrence never ran (launch failure);
// absmax ~0.09            => ran but computed wrong data.
// ---------------------------------------------------------------------------
__global__ __launch_bounds__(64) void canary(float* __restrict__ out) {
  out[threadIdx.x] = 1.0e6f;
}

// ---------------------------------------------------------------------------
// K3: recurrence — 32 WGs x 256 threads, placement-independent.
//  COHERENCE (round-0 VERIFIED protocol, device/IF$ scope):
//   - h stores: global_store_short sc0 sc1 (write-through to IF$)
//   - flag store: __hip_atomic_store relaxed AGENT (monotonic counter)
//   - flag poll:  __hip_atomic_load  relaxed AGENT
//   - h loads: PLAIN cached b128 (every slot address is first-touch after the
//     one agent-acquire fence that drops stale aliased lines)
//  STRUCTURE:
//   - WG g owns h-cols [32g,32g+32); 4 waves = 2 batch-halves x 2 col-groups
//   - 96 Wgh^T rows per wave live ENTIRELY in VGPRs as MFMA B-fragments
//     (384 VGPRs); no LDS, no ds_read, no shfl in the loop; 3 MFMA chains
//   - gx/cand for step t+1 prefetched under the MFMA region (counted-vmcnt
//     ordering keeps the MFMA A-waits independent of these HBM loads)
//   - spin guard: any residual race becomes a visible FAIL, not a GPU hang
//  Fragment conventions identical to the round-0 PASSING kernel:
//   A-frag: row=lane&15, k=(lane>>4)*8+i;  B-frag: col=lane&15, k=(lane>>4)*8+i
//   D: col=lane&15, row=(lane>>4)*4+r
// ---------------------------------------------------------------------------
__global__ __launch_bounds__(256, 1) void recurrence(const unsigned short* __restrict__ gx,
                                                     const unsigned short* __restrict__ cand,
                                                     const unsigned short* __restrict__ WghT,
                                                     unsigned short* __restrict__ ring,
                                                     unsigned int* __restrict__ flags,
                                                     float* __restrict__ out) {
  const int g = blockIdx.x;                // owns h-cols [32g, 32g+32)
  const int tid = threadIdx.x;
  const int lane = tid & 63;
  const int wave = tid >> 6;
  const int q = lane >> 4, n = lane & 15;
  const int m16 = (wave & 1) * 16;         // batch-row tile base
  const int cg2 = wave >> 1;               // col-group 0/1
  const int colh = 32 * g + cg2 * 16 + n;  // this lane's h/gate column

  // ONE agent-acquire fence: drop stale cached lines (ring aliases e; also
  // clears flag/ring leftovers from previous harness iterations).
  __builtin_amdgcn_fence(__ATOMIC_ACQUIRE, "agent");

  // ---- stage Wgh^T into registers as MFMA B-fragments (96 x b128) ----
  bf16x8_t wR[32], wP[32], wA[32];
#pragma unroll
  for (int kt = 0; kt < 32; ++kt) {
    const size_t ko = (size_t)kt * 32 + q * 8;
    wR[kt] = *(const bf16x8_t*)(WghT + (size_t)(colh)        * HID + ko);
    wP[kt] = *(const bf16x8_t*)(WghT + (size_t)(1024 + colh) * HID + ko);
    wA[kt] = *(const bf16x8_t*)(WghT + (size_t)(2048 + colh) * HID + ko);
  }

  float h_own[4] = {0.f, 0.f, 0.f, 0.f};
  unsigned short pR[4], pP[4], pA[4], pV[4];   // gx/cand for current step
  unsigned short nR[4], nP[4], nA[4], nV[4];   // prefetch for next step

  // prologue prefetch (t = 0)
#pragma unroll
  for (int r = 0; r < 4; ++r) {
    const size_t rb = (size_t)(m16 + q * 4 + r) * SEQ;
    pR[r] = gx[rb * G3 + colh];
    pP[r] = gx[rb * G3 + 1024 + colh];
    pA[r] = gx[rb * G3 + 2048 + colh];
    pV[r] = cand[rb * HID + colh];
  }

#pragma unroll 1
  for (int t = 0; t < SEQ; ++t) {
    // ---- poll: all 32 producers published h(t) (agent/IF$-coherent) ----
    if (t > 0) {
      const unsigned int* fp = flags + (lane & 31);
      unsigned fv;
      int guard = 0;
      do {
        fv = __hip_atomic_load(fp, __ATOMIC_RELAXED, __HIP_MEMORY_SCOPE_AGENT);
      } while (__any(fv < (unsigned)t) && ++guard < 8192);
      asm volatile("" ::: "memory");   // pin h loads after the poll
    }

    const int tp = (t + 1 < SEQ) ? t + 1 : t;

    // ---- preact = h(t) @ Wgh_slice (A first-touch cached, B in regs) ----
    f32x4_t aR = (f32x4_t){0.f, 0.f, 0.f, 0.f};
    f32x4_t aP = (f32x4_t){0.f, 0.f, 0.f, 0.f};
    f32x4_t aA = (f32x4_t){0.f, 0.f, 0.f, 0.f};
    if (t > 0) {
      const unsigned short* ha = ring + ((size_t)t << 15) + (size_t)(m16 + n) * HID + q * 8;
#pragma unroll
      for (int c = 0; c < 8; ++c) {
        bf16x8_t av[4];
#pragma unroll
        for (int u = 0; u < 4; ++u)
          av[u] = *(const bf16x8_t*)(ha + (c * 4 + u) * 32);
        if (c == 0) {
          // prefetch next step's gx/cand AFTER this chunk's A-loads: the
          // A-waits (counted vmcnt) stay independent of these HBM loads,
          // and ~7 chunks of MFMA hide their latency before the drain.
#pragma unroll
          for (int r = 0; r < 4; ++r) {
            const size_t rb = (size_t)(m16 + q * 4 + r) * SEQ + tp;
            nR[r] = gx[rb * G3 + colh];
            nP[r] = gx[rb * G3 + 1024 + colh];
            nA[r] = gx[rb * G3 + 2048 + colh];
            nV[r] = cand[rb * HID + colh];
          }
        }
#pragma unroll
        for (int u = 0; u < 4; ++u) {
          aR = __builtin_amdgcn_mfma_f32_16x16x32_bf16(av[u], wR[c * 4 + u], aR, 0, 0, 0);
          aP = __builtin_amdgcn_mfma_f32_16x16x32_bf16(av[u], wP[c * 4 + u], aP, 0, 0, 0);
          aA = __builtin_amdgcn_mfma_f32_16x16x32_bf16(av[u], wA[c * 4 + u], aA, 0, 0, 0);
        }
      }
    } else {
#pragma unroll
      for (int r = 0; r < 4; ++r) {
        const size_t rb = (size_t)(m16 + q * 4 + r) * SEQ + tp;
        nR[r] = gx[rb * G3 + colh];
        nP[r] = gx[rb * G3 + 1024 + colh];
        nA[r] = gx[rb * G3 + 2048 + colh];
        nV[r] = cand[rb * HID + colh];
      }
    }

    // ---- gates + carry. D layout: col = n, row(batch) = q*4+r.
    // rho/pi/alpha for the same (row,col) sit in the SAME lane & reg index.
    unsigned short* hn = ring + ((size_t)(t + 1) << 15);
#pragma unroll
    for (int r = 0; r < 4; ++r) {
      float rho = 1.f / (1.f + __expf(-(aR[r] + bf2f(pR[r]))));
      float pi  = 1.f / (1.f + __expf(-(aP[r] + bf2f(pP[r]))));
      float al  = 1.f / (1.f + __expf(-(aA[r] + bf2f(pA[r]))));
      h_own[r] = rho * (pi * h_own[r] + al * bf2f(pV[r]));
      // write-through sc0 sc1: visible at IF$; adjacent lanes coalesce to 32B
      store_short_wt(&hn[(size_t)(m16 + q * 4 + r) * HID + colh], f2bf(h_own[r]));
    }
#pragma unroll
    for (int r = 0; r < 4; ++r) { pR[r] = nR[r]; pP[r] = nP[r]; pA[r] = nA[r]; pV[r] = nV[r]; }

    // publish: drain own stores to fabric (also completes prefetches), WG
    // rendezvous, one agent-scope flag store (monotonic counter)
    asm volatile("s_waitcnt vmcnt(0)" ::: "memory");
    __syncthreads();
    if (tid == 0)
      __hip_atomic_store(&flags[g], (unsigned)(t + 1),
                         __ATOMIC_RELAXED, __HIP_MEMORY_SCOPE_AGENT);
  }

#pragma unroll
  for (int r = 0; r < 4; ++r)
    out[(size_t)(m16 + q * 4 + r) * HID + colh] = h_own[r];
}

// ---------------------------------------------------------------------------
// launcher
// ---------------------------------------------------------------------------
extern "C" void kernel_launch(void* const* d_in, const int* in_sizes, int n_in,
                              void* d_out, int out_size, void* d_ws, size_t ws_size,
                              hipStream_t stream) {
  const int*   x     = (const int*)d_in[0];
  const float* embed = (const float*)d_in[1];
  const float* Wc    = (const float*)d_in[2];
  const float* bc    = (const float*)d_in[3];
  const float* Wgx   = (const float*)d_in[4];
  const float* bgx   = (const float*)d_in[5];
  const float* Wgh   = (const float*)d_in[6];
  float* out = (float*)d_out;

  char* base = (char*)d_ws;
  unsigned short* e    = (unsigned short*)(base);                       // 32768x1024 bf16 = 64 MiB
  unsigned short* Bp   = (unsigned short*)(base + 67108864);            // 4096x1024 bf16  = 8 MiB
  unsigned short* WghT = (unsigned short*)(base + 75497472);            // 3072x1024 bf16  = 6 MiB
  unsigned short* gxb  = (unsigned short*)(base + 81788928);            // 32768x3072 bf16 = 192 MiB
  unsigned short* cnd  = (unsigned short*)(base + 283115520);           // 32768x1024 bf16 = 64 MiB
  // h ring: slot t = h(t), write-once, 1025 x 64KB. Aliases e + head of Bp
  // (both dead after gemm). Slot 0 is never touched (t=0 skips the matvec).
  unsigned short* ring  = (unsigned short*)(base);
  unsigned int*   flags = (unsigned int*)(base + 350224384);            // 32 u32

  transpose_cast<<<dim3(32, 96), dim3(32, 8), 0, stream>>>(Wgx, Bp, G3);
  transpose_cast<<<dim3(32, 32), dim3(32, 8), 0, stream>>>(Wc, Bp + (size_t)G3 * HID, HID);
  transpose_cast<<<dim3(32, 96), dim3(32, 8), 0, stream>>>(Wgh, WghT, G3);

  gather_cast<<<dim3(NROWS), dim3(256), 0, stream>>>(x, embed, e);

  gemm_fused<<<dim3(256, 32), dim3(256), 0, stream>>>(e, Bp, bgx, bc, gxb, cnd);

  // zero flags AFTER gemm, before recurrence
  init_state<<<dim3(1), dim3(64), 0, stream>>>(flags);

  // diagnostic sentinel: overwritten by recurrence; survives iff it never runs
  canary<<<dim3(1), dim3(64), 0, stream>>>(out);

  // 32 WGs x 256 thr (~460 VGPR -> 1 WG/CU): 8x under coop capacity.
  // Coop launch guarantees co-residency; if the pre-check rejects it for any
  // reason, fall back to a plain launch (32 WGs are trivially co-resident;
  // the spin guard converts any residual pathology into a visible FAIL).
  void* args[] = {(void*)&gxb, (void*)&cnd, (void*)&WghT, (void*)&ring,
                  (void*)&flags, (void*)&out};
  hipError_t cerr = hipLaunchCooperativeKernel((const void*)recurrence,
                                               dim3(NWORK), dim3(256), args, 0, stream);
  if (cerr != hipSuccess) {
    recurrence<<<dim3(NWORK), dim3(256), 0, stream>>>(gxb, cnd, WghT, ring, flags, out);
  }
}

// Round 7
// 8255.101 us; speedup vs baseline: 1.1933x; 1.1933x over previous
//
#include <hip/hip_runtime.h>
#include <cstdint>
#include <cstddef>

// ---------------------------------------------------------------------------
// Problem constants (ARU recurrence): B=32, S=1024, H=1024, 3H=3072
// ---------------------------------------------------------------------------
#define HID   1024
#define BATCH 32
#define SEQ   1024
#define NROWS 32768   /* BATCH*SEQ */
#define G3    3072
#define NWORK 32      /* recurrence worker WGs; WG g owns h-cols [32g,32g+32) */
#define HSLOT 32768   /* elements per h ring slot = BATCH*HID */

typedef __attribute__((ext_vector_type(8))) short bf16x8_t;
typedef __attribute__((ext_vector_type(4))) float f32x4_t;

__device__ __forceinline__ unsigned short f2bf(float f) {
  unsigned u = __float_as_uint(f);
  u += 0x7FFFu + ((u >> 16) & 1u);       // round-to-nearest-even
  return (unsigned short)(u >> 16);
}
__device__ __forceinline__ float bf2f(unsigned short s) {
  return __uint_as_float(((unsigned)s) << 16);
}

// write-through device-coherent 16-bit store: visible at the device coherence
// point (IF$) — VERIFIED protocol (round-0 and round-5 passing kernels).
__device__ __forceinline__ void store_short_wt(unsigned short* p, unsigned short v) {
  asm volatile("global_store_short %0, %1, off sc0 sc1"
               :: "v"(p), "v"((unsigned)v) : "memory");
}

// ---------------------------------------------------------------------------
// K0: transpose + cast  W (1024 x N) fp32  ->  WT (N x 1024) bf16
// ---------------------------------------------------------------------------
__global__ __launch_bounds__(256) void transpose_cast(const float* __restrict__ in,
                                                      unsigned short* __restrict__ out,
                                                      int N) {
  __shared__ float tile[32][33];
  int k0 = blockIdx.x * 32, n0 = blockIdx.y * 32;
  int tx = threadIdx.x, ty = threadIdx.y;   // (32,8)
#pragma unroll
  for (int i = 0; i < 4; ++i)
    tile[ty + 8 * i][tx] = in[(size_t)(k0 + ty + 8 * i) * N + n0 + tx];
  __syncthreads();
#pragma unroll
  for (int i = 0; i < 4; ++i)
    out[(size_t)(n0 + ty + 8 * i) * HID + k0 + tx] = f2bf(tile[tx][ty + 8 * i]);
}

// ---------------------------------------------------------------------------
// K1: e = bf16(embed[x])   (32768 x 1024)
// ---------------------------------------------------------------------------
__global__ __launch_bounds__(256) void gather_cast(const int* __restrict__ x,
                                                   const float* __restrict__ embed,
                                                   unsigned short* __restrict__ e) {
  int r = blockIdx.x;
  int t = threadIdx.x;
  int tok = x[r];
  const float4* src = (const float4*)(embed + (size_t)tok * HID);
  float4 v = src[t];
  ushort4 o;
  o.x = f2bf(v.x); o.y = f2bf(v.y); o.z = f2bf(v.z); o.w = f2bf(v.w);
  ((ushort4*)(e + (size_t)r * HID))[t] = o;
}

// ---------------------------------------------------------------------------
// K2: fused GEMM  C = e(32768x1024) @ B'(1024x4096)   [B' stored as (4096x1024)]
//     Output is REPACKED s-major for the recurrence's per-step locality:
//       row2 = s*32 + b   (s = m & 1023, b = m >> 10)
//     cols [0,3072): gate_x = C + bgx   (bf16, gx[row2*G3 + n])
//     cols [3072,4096): cand = tanh(C + bc) (bf16, cand[row2*HID + n-G3])
// ---------------------------------------------------------------------------
__global__ __launch_bounds__(256) void gemm_fused(const unsigned short* __restrict__ A,
                                                  const unsigned short* __restrict__ B,
                                                  const float* __restrict__ bgx,
                                                  const float* __restrict__ bc,
                                                  unsigned short* __restrict__ gx,
                                                  unsigned short* __restrict__ cand) {
  __shared__ unsigned short As[128 * 32];
  __shared__ unsigned short Bs[128 * 32];
  const int bm = blockIdx.x * 128, bn = blockIdx.y * 128;
  const int t = threadIdx.x;
  const int wave = t >> 6, lane = t & 63;
  const int q = lane >> 4, nidx = lane & 15;
  const int wm = (wave & 1) * 64, wn = (wave >> 1) * 64;
  const int sr = t >> 2;
  const int kofs = (t & 3) * 8;

  f32x4_t acc[4][4];
#pragma unroll
  for (int i = 0; i < 4; ++i)
#pragma unroll
    for (int j = 0; j < 4; ++j) acc[i][j] = (f32x4_t){0.f, 0.f, 0.f, 0.f};

#pragma unroll 1
  for (int kt = 0; kt < HID; kt += 32) {
    __syncthreads();
#pragma unroll
    for (int c = 0; c < 2; ++c) {
      int row = c * 64 + sr;
      *(uint4*)(&As[row * 32 + kofs]) = *(const uint4*)(&A[(size_t)(bm + row) * HID + kt + kofs]);
      *(uint4*)(&Bs[row * 32 + kofs]) = *(const uint4*)(&B[(size_t)(bn + row) * HID + kt + kofs]);
    }
    __syncthreads();
    bf16x8_t af[4], bfr[4];
#pragma unroll
    for (int i = 0; i < 4; ++i)
      af[i] = *(const bf16x8_t*)(&As[(wm + i * 16 + nidx) * 32 + q * 8]);
#pragma unroll
    for (int j = 0; j < 4; ++j)
      bfr[j] = *(const bf16x8_t*)(&Bs[(wn + j * 16 + nidx) * 32 + q * 8]);
#pragma unroll
    for (int i = 0; i < 4; ++i)
#pragma unroll
      for (int j = 0; j < 4; ++j)
        acc[i][j] = __builtin_amdgcn_mfma_f32_16x16x32_bf16(af[i], bfr[j], acc[i][j], 0, 0, 0);
  }

#pragma unroll
  for (int i = 0; i < 4; ++i) {
#pragma unroll
    for (int j = 0; j < 4; ++j) {
#pragma unroll
      for (int reg = 0; reg < 4; ++reg) {
        int m = bm + wm + i * 16 + q * 4 + reg;
        int s = m & (SEQ - 1), b = m >> 10;
        size_t row2 = (size_t)s * BATCH + b;
        int n = bn + wn + j * 16 + nidx;
        float v = acc[i][j][reg];
        if (n < G3) {
          gx[row2 * G3 + n] = f2bf(v + bgx[n]);
        } else {
          int nc = n - G3;
          cand[row2 * HID + nc] = f2bf(tanhf(v + bc[nc]));
        }
      }
    }
  }
}

// ---------------------------------------------------------------------------
// K3a: zero flags[32]  (ring slot 0 is never read: t=0 skips the matvec)
// ---------------------------------------------------------------------------
__global__ __launch_bounds__(64) void init_state(unsigned int* __restrict__ fx) {
  int t = threadIdx.x;
  if (t < 32) fx[t] = 0u;
}

// ---------------------------------------------------------------------------
// K3b: canary — diagnostic sentinel, overwritten by a successful recurrence.
// absmax ~1e6 => recurrence never ran; ~0.09 => ran but wrong data.
// ---------------------------------------------------------------------------
__global__ __launch_bounds__(64) void canary(float* __restrict__ out) {
  out[threadIdx.x] = 1.0e6f;
}

// ---------------------------------------------------------------------------
// K3: recurrence — 32 WGs x 512 threads (8 waves), K-split for TRUE register
// residency of Wgh^T.
//  Wave roles: wave = (mh | cg<<1 | kh<<2):
//    mh: batch half (rows mh*16..+16), cg: col group (cols 32g+cg*16..+16),
//    kh: K half ([kh*512, kh*512+512)).
//  Weights: 3 gates x 16 K-frags = 48 bf16x8 = 192 VGPRs/wave -> total ~250,
//  fits the 256-VGPR cap a 512-thread block imposes (8 waves = 2/SIMD), so
//  the compiler KEEPS them resident (round-5's 384-frag plan was silently
//  rematerialized at VGPR_Count=240 -> per-step reload = the 8.85us/step).
//  Per step: all waves MFMA their K-half partials; kh=1 adds gx (additive
//  preact term) into its partials and writes them to LDS; barrier; kh=0 adds
//  partner partials, computes gates (cand only), stores h write-through.
//  COHERENCE: identical to round-5 PASSING kernel (sc0sc1 h stores, agent
//  flag store/poll, plain first-touch h loads, one agent-acquire fence).
// ---------------------------------------------------------------------------
__global__ __launch_bounds__(512, 2) void recurrence(const unsigned short* __restrict__ gx,
                                                     const unsigned short* __restrict__ cand,
                                                     const unsigned short* __restrict__ WghT,
                                                     unsigned short* __restrict__ ring,
                                                     unsigned int* __restrict__ flags,
                                                     float* __restrict__ out) {
  const int g = blockIdx.x;                // owns h-cols [32g, 32g+32)
  const int tid = threadIdx.x;
  const int lane = tid & 63;
  const int wave = tid >> 6;               // 0..7
  const int q = lane >> 4, n = lane & 15;
  const int mh = (wave & 1) * 16;          // batch-half base
  const int cg = (wave >> 1) & 1;          // col-group
  const int kh = wave >> 2;                // K-half
  const int colh = 32 * g + cg * 16 + n;   // this lane's h/gate column
  const int kbase = kh * 512;

  __shared__ f32x4_t red[3][4][64];        // [gate][wave&3][lane] partials

  // ONE agent-acquire fence: drop stale cached lines (ring aliases e; also
  // clears flag/ring leftovers from previous harness iterations).
  __builtin_amdgcn_fence(__ATOMIC_ACQUIRE, "agent");

  // ---- stage this wave's K-half of Wgh^T into registers (48 x b128) ----
  bf16x8_t wR[16], wP[16], wA[16];
#pragma unroll
  for (int kt = 0; kt < 16; ++kt) {
    const size_t ko = (size_t)(kbase + kt * 32 + q * 8);
    wR[kt] = *(const bf16x8_t*)(WghT + (size_t)(colh)        * HID + ko);
    wP[kt] = *(const bf16x8_t*)(WghT + (size_t)(1024 + colh) * HID + ko);
    wA[kt] = *(const bf16x8_t*)(WghT + (size_t)(2048 + colh) * HID + ko);
  }

  float h_own[4] = {0.f, 0.f, 0.f, 0.f};
  // prefetch state: kh=0 uses [0..3] = cand; kh=1 uses [0..11] = gx r/p/a
  unsigned short pcur[12], pnext[12];

  // prologue prefetch (t = 0); s-major layout: row2 = t*32 + batch_row
  if (kh == 0) {
#pragma unroll
    for (int r = 0; r < 4; ++r)
      pcur[r] = cand[(size_t)(mh + q * 4 + r) * HID + colh];
#pragma unroll
    for (int r = 4; r < 12; ++r) pcur[r] = 0;
  } else {
#pragma unroll
    for (int r = 0; r < 4; ++r) {
      const size_t rb = (size_t)(mh + q * 4 + r) * G3;
      pcur[r]     = gx[rb + colh];
      pcur[4 + r] = gx[rb + 1024 + colh];
      pcur[8 + r] = gx[rb + 2048 + colh];
    }
  }

#pragma unroll 1
  for (int t = 0; t < SEQ; ++t) {
    // ---- poll: all 32 producers published h(t) (agent/IF$-coherent) ----
    if (t > 0) {
      const unsigned int* fp = flags + (lane & 31);
      unsigned fv;
      int guard = 0;
      do {
        fv = __hip_atomic_load(fp, __ATOMIC_RELAXED, __HIP_MEMORY_SCOPE_AGENT);
      } while (__any(fv < (unsigned)t) && ++guard < 8192);
      asm volatile("" ::: "memory");   // pin h loads after the poll
    }

    const int tp = (t + 1 < SEQ) ? t + 1 : t;

    // ---- partial preact over this wave's K-half (A first-touch, B in regs)
    f32x4_t aR = (f32x4_t){0.f, 0.f, 0.f, 0.f};
    f32x4_t aP = (f32x4_t){0.f, 0.f, 0.f, 0.f};
    f32x4_t aA = (f32x4_t){0.f, 0.f, 0.f, 0.f};
    if (t > 0) {
      const unsigned short* ha = ring + ((size_t)t << 15)
                               + (size_t)(mh + n) * HID + kbase + q * 8;
#pragma unroll
      for (int c = 0; c < 8; ++c) {
        bf16x8_t av0 = *(const bf16x8_t*)(ha + (c * 2 + 0) * 32);
        bf16x8_t av1 = *(const bf16x8_t*)(ha + (c * 2 + 1) * 32);
        if (c == 0) {
          // next-step prefetch issued under the MFMA region
          if (kh == 0) {
#pragma unroll
            for (int r = 0; r < 4; ++r)
              pnext[r] = cand[((size_t)tp * BATCH + mh + q * 4 + r) * HID + colh];
          } else {
#pragma unroll
            for (int r = 0; r < 4; ++r) {
              const size_t rb = ((size_t)tp * BATCH + mh + q * 4 + r) * G3;
              pnext[r]     = gx[rb + colh];
              pnext[4 + r] = gx[rb + 1024 + colh];
              pnext[8 + r] = gx[rb + 2048 + colh];
            }
          }
        }
        aR = __builtin_amdgcn_mfma_f32_16x16x32_bf16(av0, wR[c * 2], aR, 0, 0, 0);
        aP = __builtin_amdgcn_mfma_f32_16x16x32_bf16(av0, wP[c * 2], aP, 0, 0, 0);
        aA = __builtin_amdgcn_mfma_f32_16x16x32_bf16(av0, wA[c * 2], aA, 0, 0, 0);
        aR = __builtin_amdgcn_mfma_f32_16x16x32_bf16(av1, wR[c * 2 + 1], aR, 0, 0, 0);
        aP = __builtin_amdgcn_mfma_f32_16x16x32_bf16(av1, wP[c * 2 + 1], aP, 0, 0, 0);
        aA = __builtin_amdgcn_mfma_f32_16x16x32_bf16(av1, wA[c * 2 + 1], aA, 0, 0, 0);
      }
    } else {
      // t = 0: no h yet; just issue the t=1 prefetch
      if (kh == 0) {
#pragma unroll
        for (int r = 0; r < 4; ++r)
          pnext[r] = cand[((size_t)tp * BATCH + mh + q * 4 + r) * HID + colh];
      } else {
#pragma unroll
        for (int r = 0; r < 4; ++r) {
          const size_t rb = ((size_t)tp * BATCH + mh + q * 4 + r) * G3;
          pnext[r]     = gx[rb + colh];
          pnext[4 + r] = gx[rb + 1024 + colh];
          pnext[8 + r] = gx[rb + 2048 + colh];
        }
      }
    }

    // ---- kh=1: fold gx into partials, export via LDS ----
    if (kh == 1) {
#pragma unroll
      for (int r = 0; r < 4; ++r) {
        aR[r] += bf2f(pcur[r]);
        aP[r] += bf2f(pcur[4 + r]);
        aA[r] += bf2f(pcur[8 + r]);
      }
      red[0][wave & 3][lane] = aR;
      red[1][wave & 3][lane] = aP;
      red[2][wave & 3][lane] = aA;
    }
    __syncthreads();

    // ---- kh=0: combine, gates, carry, h store ----
    if (kh == 0) {
      f32x4_t bR = red[0][wave & 3][lane];
      f32x4_t bP = red[1][wave & 3][lane];
      f32x4_t bA = red[2][wave & 3][lane];
      unsigned short* hn = ring + ((size_t)(t + 1) << 15);
#pragma unroll
      for (int r = 0; r < 4; ++r) {
        float rho = 1.f / (1.f + __expf(-(aR[r] + bR[r])));
        float pi  = 1.f / (1.f + __expf(-(aP[r] + bP[r])));
        float al  = 1.f / (1.f + __expf(-(aA[r] + bA[r])));
        h_own[r] = rho * (pi * h_own[r] + al * bf2f(pcur[r]));
        store_short_wt(&hn[(size_t)(mh + q * 4 + r) * HID + colh], f2bf(h_own[r]));
      }
      // drain own write-through h stores to fabric before publishing
      asm volatile("s_waitcnt vmcnt(0)" ::: "memory");
    }
#pragma unroll
    for (int r = 0; r < 12; ++r) pcur[r] = pnext[r];

    __syncthreads();
    if (tid == 0)
      __hip_atomic_store(&flags[g], (unsigned)(t + 1),
                         __ATOMIC_RELAXED, __HIP_MEMORY_SCOPE_AGENT);
  }

  if (kh == 0) {
#pragma unroll
    for (int r = 0; r < 4; ++r)
      out[(size_t)(mh + q * 4 + r) * HID + colh] = h_own[r];
  }
}

// ---------------------------------------------------------------------------
// launcher
// ---------------------------------------------------------------------------
extern "C" void kernel_launch(void* const* d_in, const int* in_sizes, int n_in,
                              void* d_out, int out_size, void* d_ws, size_t ws_size,
                              hipStream_t stream) {
  const int*   x     = (const int*)d_in[0];
  const float* embed = (const float*)d_in[1];
  const float* Wc    = (const float*)d_in[2];
  const float* bc    = (const float*)d_in[3];
  const float* Wgx   = (const float*)d_in[4];
  const float* bgx   = (const float*)d_in[5];
  const float* Wgh   = (const float*)d_in[6];
  float* out = (float*)d_out;

  char* base = (char*)d_ws;
  unsigned short* e    = (unsigned short*)(base);                       // 32768x1024 bf16 = 64 MiB
  unsigned short* Bp   = (unsigned short*)(base + 67108864);            // 4096x1024 bf16  = 8 MiB
  unsigned short* WghT = (unsigned short*)(base + 75497472);            // 3072x1024 bf16  = 6 MiB
  unsigned short* gxb  = (unsigned short*)(base + 81788928);            // 32768x3072 bf16 = 192 MiB (s-major)
  unsigned short* cnd  = (unsigned short*)(base + 283115520);           // 32768x1024 bf16 = 64 MiB (s-major)
  // h ring: slot t = h(t), write-once, 1025 x 64KB. Aliases e + head of Bp
  // (both dead after gemm). Slot 0 is never touched (t=0 skips the matvec).
  unsigned short* ring  = (unsigned short*)(base);
  unsigned int*   flags = (unsigned int*)(base + 350224384);            // 32 u32

  transpose_cast<<<dim3(32, 96), dim3(32, 8), 0, stream>>>(Wgx, Bp, G3);
  transpose_cast<<<dim3(32, 32), dim3(32, 8), 0, stream>>>(Wc, Bp + (size_t)G3 * HID, HID);
  transpose_cast<<<dim3(32, 96), dim3(32, 8), 0, stream>>>(Wgh, WghT, G3);

  gather_cast<<<dim3(NROWS), dim3(256), 0, stream>>>(x, embed, e);

  gemm_fused<<<dim3(256, 32), dim3(256), 0, stream>>>(e, Bp, bgx, bc, gxb, cnd);

  // zero flags AFTER gemm, before recurrence
  init_state<<<dim3(1), dim3(64), 0, stream>>>(flags);

  // diagnostic sentinel: overwritten by recurrence; survives iff it never runs
  canary<<<dim3(1), dim3(64), 0, stream>>>(out);

  // 32 WGs x 512 thr (8 waves, <=256 VGPR). Coop launch for co-residency;
  // fall back to plain launch (32 WGs trivially co-resident; spin guard
  // converts any pathology into a visible FAIL, never a hang).
  void* args[] = {(void*)&gxb, (void*)&cnd, (void*)&WghT, (void*)&ring,
                  (void*)&flags, (void*)&out};
  hipError_t cerr = hipLaunchCooperativeKernel((const void*)recurrence,
                                               dim3(NWORK), dim3(512), args, 0, stream);
  if (cerr != hipSuccess) {
    recurrence<<<dim3(NWORK), dim3(512), 0, stream>>>(gxb, cnd, WghT, ring, flags, out);
  }
}